// Round 20
// baseline (169.625 us; speedup 1.0000x reference)
//
#include <hip/hip_runtime.h>
#include <hip/hip_bf16.h>
#include <math.h>

// B=32, HID=4096, NH=32, NKV=8, HS=128, BS=16, MAXS=2048, groups=4

typedef __attribute__((ext_vector_type(8))) short bf16x8;
typedef __attribute__((ext_vector_type(4))) float f32x4;

// ---------------------------------------------------------------------------
// bf16 MFMA GEMM v3 (R16, proven): one block per 16n x 32m C-tile; 8 waves =
// K=512 splits; w-fragment shared by both m-halves; LDS reduce; no atomics.
// ---------------------------------------------------------------------------
__device__ __forceinline__ short f2bfs(float f) {
    __hip_bfloat16 h = __float2bfloat16(f);
    unsigned short u;
    __builtin_memcpy(&u, &h, 2);
    return (short)u;
}
__device__ __forceinline__ bf16x8 cvt8(float4 a, float4 b) {
    bf16x8 r;
    r[0] = f2bfs(a.x); r[1] = f2bfs(a.y); r[2] = f2bfs(a.z); r[3] = f2bfs(a.w);
    r[4] = f2bfs(b.x); r[5] = f2bfs(b.y); r[6] = f2bfs(b.z); r[7] = f2bfs(b.w);
    return r;
}

__device__ __forceinline__ void mfma_block8(
    const float* __restrict__ xp0, const float* __restrict__ xp1,
    const float* __restrict__ wp, float* __restrict__ dst, int dstr, int n0)
{
    __shared__ float red[8][64][8];
    int wave = threadIdx.x >> 6, lane = threadIdx.x & 63;
    f32x4 acc0 = {0.f, 0.f, 0.f, 0.f};
    f32x4 acc1 = {0.f, 0.f, 0.f, 0.f};
#pragma unroll 4
    for (int s = 0; s < 16; ++s) {
        float4 wa  = *(const float4*)(wp  + s * 32);
        float4 wb  = *(const float4*)(wp  + s * 32 + 4);
        float4 x0a = *(const float4*)(xp0 + s * 32);
        float4 x0b = *(const float4*)(xp0 + s * 32 + 4);
        float4 x1a = *(const float4*)(xp1 + s * 32);
        float4 x1b = *(const float4*)(xp1 + s * 32 + 4);
        bf16x8 wf = cvt8(wa, wb);
        acc0 = __builtin_amdgcn_mfma_f32_16x16x32_bf16(cvt8(x0a, x0b), wf, acc0, 0, 0, 0);
        acc1 = __builtin_amdgcn_mfma_f32_16x16x32_bf16(cvt8(x1a, x1b), wf, acc1, 0, 0, 0);
    }
#pragma unroll
    for (int j = 0; j < 4; ++j) { red[wave][lane][j] = acc0[j]; red[wave][lane][4 + j] = acc1[j]; }
    __syncthreads();
    if (threadIdx.x < 128) {
        int l = threadIdx.x & 63, half = threadIdx.x >> 6;
        int ccol = n0 + (l & 15);
        int rbase = half * 16 + ((l >> 4) << 2);
#pragma unroll
        for (int j = 0; j < 4; ++j) {
            int e = (half << 2) + j;
            float s = red[0][l][e] + red[1][l][e] + red[2][l][e] + red[3][l][e]
                    + red[4][l][e] + red[5][l][e] + red[6][l][e] + red[7][l][e];
            dst[(size_t)(rbase + j) * dstr + ccol] = s;
        }
    }
}

// grid = 384 blocks x 512 thr (256 q-tiles, 64 k, 64 v)
__global__ __launch_bounds__(512) void qkv_mfma(
    const float* __restrict__ x, const float* __restrict__ wq,
    const float* __restrict__ wk, const float* __restrict__ wv,
    float* __restrict__ qb, float* __restrict__ knb, float* __restrict__ vnb)
{
    int nt = blockIdx.x;
    int wave = threadIdx.x >> 6, lane = threadIdx.x & 63;
    const float* w; float* dst; int dstr; int n0;
    if (nt < 256)      { w = wq; n0 = nt * 16;         dst = qb;  dstr = 4096; }
    else if (nt < 320) { w = wk; n0 = (nt - 256) * 16; dst = knb; dstr = 1024; }
    else               { w = wv; n0 = (nt - 320) * 16; dst = vnb; dstr = 1024; }
    int row = lane & 15, kq = (lane >> 4) << 3;
    int kbase = wave << 9;
    const float* xp0 = x + (size_t)row * 4096 + kbase + kq;
    const float* xp1 = xp0 + (size_t)16 * 4096;
    const float* wp  = w + (size_t)(n0 + row) * 4096 + kbase + kq;
    mfma_block8(xp0, xp1, wp, dst, dstr, n0);
}

// grid = 256 blocks x 512 thr
__global__ __launch_bounds__(512) void wo_mfma(
    const float* __restrict__ attn, const float* __restrict__ wo,
    float* __restrict__ out)
{
    int nt = blockIdx.x;
    int wave = threadIdx.x >> 6, lane = threadIdx.x & 63;
    int n0 = nt * 16;
    int row = lane & 15, kq = (lane >> 4) << 3;
    int kbase = wave << 9;
    const float* xp0 = attn + (size_t)row * 4096 + kbase + kq;
    const float* xp1 = xp0 + (size_t)16 * 4096;
    const float* wp  = wo + (size_t)(n0 + row) * 4096 + kbase + kq;
    mfma_block8(xp0, xp1, wp, out, 4096, n0);
}

// ---------------------------------------------------------------------------
// Flash-decode attention v11 = v10 math (contiguous lane slicing, lane-local
// rope) + FULL 8-head co-scheduling WITH TEMPORAL COHESION: one 512-thread
// block owns all 8 kv-heads of a (b, 128-chunk), and a block barrier every 2
// rounds keeps the 8 h-waves' touches of each 4KB KV row inside a tight
// window for the whole stream (v6's co-scheduling gave the only real attn
// delta, -4.6us; its mechanism -- DRAM row locality across heads -- decays
// as waves drift; v8 also cut co-residence to 2 heads. This completes it.)
// Barrier paths are block-uniform (cend/nr/hasTail depend only on (b,c)).
// ---------------------------------------------------------------------------
#define MUL4(V, S) { V.x *= S; V.y *= S; V.z *= S; V.w *= S; }
#define FMA4(O, P, V) { O.x = fmaf(P, V.x, O.x); O.y = fmaf(P, V.y, O.y); \
                        O.z = fmaf(P, V.z, O.z); O.w = fmaf(P, V.w, O.w); }
#define DOT8(S, QA, QB, K0, K1) { \
    S = fmaf(QA.x, K0.x, S); S = fmaf(QA.y, K0.y, S); \
    S = fmaf(QA.z, K0.z, S); S = fmaf(QA.w, K0.w, S); \
    S = fmaf(QB.x, K1.x, S); S = fmaf(QB.y, K1.y, S); \
    S = fmaf(QB.z, K1.z, S); S = fmaf(QB.w, K1.w, S); }
#define RED16(X) { X += __shfl_xor(X, 1, 64); X += __shfl_xor(X, 2, 64); \
                   X += __shfl_xor(X, 4, 64); X += __shfl_xor(X, 8, 64); }
#define REDG_SUM(X) { X += __shfl_xor(X, 16, 64); X += __shfl_xor(X, 32, 64); }
#define REDG_MAX(X) { X = fmaxf(X, __shfl_xor(X, 16, 64)); \
                      X = fmaxf(X, __shfl_xor(X, 32, 64)); }
#define REDG_SUM4(V) { REDG_SUM(V.x) REDG_SUM(V.y) REDG_SUM(V.z) REDG_SUM(V.w) }

// lane-local rope: A = dims 4i..4i+3 (first half), B = dims 64+4i.. (second)
#define ROPE8(A, B) { \
    float2 c0 = cs[isl + 0], c1 = cs[isl + 1], c2 = cs[isl + 2], c3 = cs[isl + 3]; \
    float a0 = A.x, a1 = A.y, a2 = A.z, a3 = A.w; \
    A.x = fmaf(-B.x, c0.y, a0 * c0.x); \
    A.y = fmaf(-B.y, c1.y, a1 * c1.x); \
    A.z = fmaf(-B.z, c2.y, a2 * c2.x); \
    A.w = fmaf(-B.w, c3.y, a3 * c3.x); \
    B.x = fmaf(a0, c0.y, B.x * c0.x); \
    B.y = fmaf(a1, c1.y, B.y * c1.x); \
    B.z = fmaf(a2, c2.y, B.z * c2.x); \
    B.w = fmaf(a3, c3.y, B.w * c3.x); }

#define ALOADR(S, r_) { \
    int sl = ss[((r_) << 2) + g]; \
    const float* kp = kc + (size_t)sl * 1024 + hoff + isl; \
    const float* vp = vc + (size_t)sl * 1024 + hoff + isl; \
    S##k0 = *(const float4*)(kp); S##k1 = *(const float4*)(kp + 64); \
    S##v0 = *(const float4*)(vp); S##v1 = *(const float4*)(vp + 64); }

#define OUPD(s_, m_, l_, Oa_, Ob_, V0_, V1_, vld_) { \
    if (s_ > m_) { \
        float c_ = __expf(m_ - s_); \
        l_ *= c_; MUL4(Oa_, c_) MUL4(Ob_, c_) \
        m_ = s_; \
    } \
    float pe_ = vld_ ? __expf(s_ - m_) : 0.f; \
    l_ += pe_; \
    FMA4(Oa_, pe_, V0_) FMA4(Ob_, pe_, V1_) }

#define ACOMP(S, r_) { \
    float s0 = 0.f, s1 = 0.f, s2 = 0.f, s3 = 0.f; \
    DOT8(s0, q0a, q0b, S##k0, S##k1) \
    DOT8(s1, q1a, q1b, S##k0, S##k1) \
    DOT8(s2, q2a, q2b, S##k0, S##k1) \
    DOT8(s3, q3a, q3b, S##k0, S##k1) \
    RED16(s0) RED16(s1) RED16(s2) RED16(s3) \
    int vld = (((r_) << 2) + g) < cend; \
    if (!vld) { s0 = s1 = s2 = s3 = -INFINITY; } \
    OUPD(s0, m0, l0, o0a, o0b, S##v0, S##v1, vld) \
    OUPD(s1, m1, l1, o1a, o1b, S##v0, S##v1, vld) \
    OUPD(s2, m2, l2, o2a, o2b, S##v0, S##v1, vld) \
    OUPD(s3, m3, l3, o3a, o3b, S##v0, S##v1, vld) }

__global__ __launch_bounds__(512, 1) void attn_kernel(
    const float* __restrict__ kc, const float* __restrict__ vc,
    const float* __restrict__ qb, const float* __restrict__ knb,
    const float* __restrict__ vnb,
    const int* __restrict__ btab, const int* __restrict__ lens,
    float* __restrict__ part)
{
    int bid = blockIdx.x;
    int c = bid >> 5, b = bid & 31;     // chunk-major for CU balance
    int len = lens[b];
    int p0 = c << 7;
    if (p0 >= len) return;
    int last = len - 1;                 // new-token position
    int cend = min(last - p0, 128);     // cached positions in this chunk
    int hasTail = (last - p0) < 128;
    int nr = (cend + 3) >> 2;           // block-uniform

    __shared__ int ss[128];
    __shared__ float2 cs[64];           // rope cos/sin for pos = last

    int t = threadIdx.x;                // 0..511
    int h = t >> 6;                     // wave = kv-head 0..7
    int lane = t & 63;
    int g = lane >> 4;                  // position-in-round 0..3
    int i = lane & 15;
    int isl = i << 2;                   // dim slice base (4 floats; +64 pair)
    int hoff = h * 128;

    if (t < 64) {                       // rope table: d' = t
        float inv = exp2f(-(float)t * 0.20762050593046014f);
        float fr = (float)last * inv;
        float s_, c_;
        sincosf(fr, &s_, &c_);
        cs[t] = make_float2(c_, s_);
    } else if (t < 128) {               // slot table (all entries valid slots)
        int idx2 = (t - 64) << 1;
        int p = p0 + idx2;
        int bt = btab[b * 128 + (p >> 4)];
        ss[idx2]     = bt * 16 + (p & 15);
        ss[idx2 + 1] = bt * 16 + (p & 15) + 1;
    }
    __syncthreads();

    // q for this kv-head's 4 GQA heads: load (contig halves), ROPE, prescale
    const float scale = 0.08838834764831845f;   // 1/sqrt(128)
    const float* qrow = qb + (size_t)b * 4096 + (size_t)h * 512;
    float4 q0a = *(const float4*)(qrow + isl),       q0b = *(const float4*)(qrow + 64 + isl);
    float4 q1a = *(const float4*)(qrow + 128 + isl), q1b = *(const float4*)(qrow + 192 + isl);
    float4 q2a = *(const float4*)(qrow + 256 + isl), q2b = *(const float4*)(qrow + 320 + isl);
    float4 q3a = *(const float4*)(qrow + 384 + isl), q3b = *(const float4*)(qrow + 448 + isl);
    ROPE8(q0a, q0b) ROPE8(q1a, q1b) ROPE8(q2a, q2b) ROPE8(q3a, q3b)
    MUL4(q0a, scale) MUL4(q0b, scale) MUL4(q1a, scale) MUL4(q1b, scale)
    MUL4(q2a, scale) MUL4(q2b, scale) MUL4(q3a, scale) MUL4(q3b, scale)

    float m0 = -INFINITY, m1 = -INFINITY, m2 = -INFINITY, m3 = -INFINITY;
    float l0 = 0.f, l1 = 0.f, l2 = 0.f, l3 = 0.f;
    float4 o0a = {0,0,0,0}, o0b = {0,0,0,0}, o1a = {0,0,0,0}, o1b = {0,0,0,0};
    float4 o2a = {0,0,0,0}, o2b = {0,0,0,0}, o3a = {0,0,0,0}, o3b = {0,0,0,0};

    // ---- tail: the new-token position (rope k_new in-reg; v not roped) ----
    if (hasTail) {
        const float* kn = knb + ((size_t)b * 8 + h) * 128 + isl;
        const float* vn = vnb + ((size_t)b * 8 + h) * 128 + isl;
        float4 tk0 = *(const float4*)(kn), tk1 = *(const float4*)(kn + 64);
        float4 tv0 = *(const float4*)(vn), tv1 = *(const float4*)(vn + 64);
        ROPE8(tk0, tk1)
        float s0 = 0.f, s1 = 0.f, s2 = 0.f, s3 = 0.f;
        DOT8(s0, q0a, q0b, tk0, tk1)
        DOT8(s1, q1a, q1b, tk0, tk1)
        DOT8(s2, q2a, q2b, tk0, tk1)
        DOT8(s3, q3a, q3b, tk0, tk1)
        RED16(s0) RED16(s1) RED16(s2) RED16(s3)
        int vld = (g == 0);
        if (!vld) { s0 = s1 = s2 = s3 = -INFINITY; }
        OUPD(s0, m0, l0, o0a, o0b, tv0, tv1, vld)
        OUPD(s1, m1, l1, o1a, o1b, tv0, tv1, vld)
        OUPD(s2, m2, l2, o2a, o2b, tv0, tv1, vld)
        OUPD(s3, m3, l3, o3a, o3b, tv0, tv1, vld)
    }

    // ---- main loop: cache streaming; barrier every 2 rounds keeps the 8
    //      h-waves' row-touches temporally clustered (block-uniform bounds) --
    float4 ak0, ak1, av0, av1;
    float4 bk0, bk1, bv0, bv1;
    if (nr > 0) {
        ALOADR(a, 0)
        if (1 < nr) ALOADR(b, 1)
        for (int r = 0; r < nr; r += 2) {
            __syncthreads();            // cohesion barrier (uniform path)
            ACOMP(a, r)
            if (r + 2 < nr) ALOADR(a, r + 2)
            if (r + 1 >= nr) break;
            ACOMP(b, r + 1)
            if (r + 3 < nr) ALOADR(b, r + 3)
        }
    }

    // merge the 4 subgroup partial softmaxes (once per wave)
    float M0 = m0, M1 = m1, M2 = m2, M3 = m3;
    REDG_MAX(M0) REDG_MAX(M1) REDG_MAX(M2) REDG_MAX(M3)
    float w0 = __expf(m0 - M0), w1 = __expf(m1 - M1);
    float w2 = __expf(m2 - M2), w3 = __expf(m3 - M3);
    float L0 = w0 * l0, L1 = w1 * l1, L2 = w2 * l2, L3 = w3 * l3;
    REDG_SUM(L0) REDG_SUM(L1) REDG_SUM(L2) REDG_SUM(L3)
    MUL4(o0a, w0) MUL4(o0b, w0) MUL4(o1a, w1) MUL4(o1b, w1)
    MUL4(o2a, w2) MUL4(o2b, w2) MUL4(o3a, w3) MUL4(o3b, w3)
    REDG_SUM4(o0a) REDG_SUM4(o0b) REDG_SUM4(o1a) REDG_SUM4(o1b)
    REDG_SUM4(o2a) REDG_SUM4(o2b) REDG_SUM4(o3a) REDG_SUM4(o3b)

    // partial layout: per (b,h,c): 4 heads x 132 floats [O[128], m, l, pad2]
    float* pgb = part + (size_t)(((b * 8 + h) * 16 + c) * 4) * 132;
    if (lane < 16) {
        *(float4*)(pgb +       isl) = o0a; *(float4*)(pgb +  64 + isl) = o0b;
        *(float4*)(pgb + 132 + isl) = o1a; *(float4*)(pgb + 196 + isl) = o1b;
        *(float4*)(pgb + 264 + isl) = o2a; *(float4*)(pgb + 328 + isl) = o2b;
        *(float4*)(pgb + 396 + isl) = o3a; *(float4*)(pgb + 460 + isl) = o3b;
    }
    if (lane == 0) {
        pgb[128] = M0; pgb[129] = L0;
        pgb[260] = M1; pgb[261] = L1;
        pgb[392] = M2; pgb[393] = L2;
        pgb[524] = M3; pgb[525] = L3;
    }
}

// grid = 256 (b*8+h), block = 256 (4 q-heads x 64 lanes)
__global__ __launch_bounds__(256) void combine_kernel(
    const float* __restrict__ part, const int* __restrict__ lens,
    float* __restrict__ attn)
{
    int b = blockIdx.x >> 3, h = blockIdx.x & 7;
    int t = threadIdx.x;
    int g = t >> 6, lane = t & 63;
    int len = lens[b];
    int nch = (len + 127) >> 7;
    const float* base = part + (size_t)(b * 8 + h) * 8448 + (size_t)g * 132;
    float M = -INFINITY;
    for (int cc = 0; cc < nch; ++cc)
        M = fmaxf(M, base[(size_t)cc * 528 + 128]);
    float denom = 0.f, a0 = 0.f, a1 = 0.f;
    int d0 = lane << 1;
    for (int cc = 0; cc < nch; ++cc) {
        const float* pg = base + (size_t)cc * 528;
        float w = __expf(pg[128] - M);
        denom += w * pg[129];
        a0 += w * pg[d0];
        a1 += w * pg[d0 + 1];
    }
    float inv = 1.f / denom;
    float* dst = attn + (size_t)b * 4096 + (size_t)(h * 4 + g) * 128 + d0;
    dst[0] = a0 * inv;
    dst[1] = a1 * inv;
}

// ---------------------------------------------------------------------------
// Workspace (floats): qb[32][4096] @0, knb[32*1024] @131072, vnb @163840,
// attn[32][4096] @196608, part[32*8*16*4*132] @327680 (~8.7MB).
// NO memsets: all outputs fully written (no atomics anywhere). 4 dispatches.
// ---------------------------------------------------------------------------
extern "C" void kernel_launch(void* const* d_in, const int* in_sizes, int n_in,
                              void* d_out, int out_size, void* d_ws, size_t ws_size,
                              hipStream_t stream)
{
    const float* x   = (const float*)d_in[0];
    const float* wq  = (const float*)d_in[1];
    const float* wk  = (const float*)d_in[2];
    const float* wv  = (const float*)d_in[3];
    const float* wo  = (const float*)d_in[4];
    const float* kc  = (const float*)d_in[5];
    const float* vc  = (const float*)d_in[6];
    const int* btab  = (const int*)d_in[8];
    const int* lens  = (const int*)d_in[10];

    float* qb   = (float*)d_ws;
    float* knb  = qb  + 32 * 4096;
    float* vnb  = knb + 32 * 1024;
    float* attn = vnb + 32 * 1024;
    float* part = attn + 32 * 4096;
    float* outp = (float*)d_out;

    qkv_mfma<<<384, 512, 0, stream>>>(x, wq, wk, wv, qb, knb, vnb);
    attn_kernel<<<512, 512, 0, stream>>>(kc, vc, qb, knb, vnb, btab, lens, part);
    combine_kernel<<<256, 256, 0, stream>>>(part, lens, attn);
    wo_mfma<<<256, 512, 0, stream>>>(attn, wo, outp);
}

// Round 21
// 153.483 us; speedup vs baseline: 1.1052x; 1.1052x over previous
//
#include <hip/hip_runtime.h>
#include <hip/hip_bf16.h>
#include <math.h>

// B=32, HID=4096, NH=32, NKV=8, HS=128, BS=16, MAXS=2048, groups=4

typedef __attribute__((ext_vector_type(8))) short bf16x8;
typedef __attribute__((ext_vector_type(4))) float f32x4;

// ---------------------------------------------------------------------------
// bf16 MFMA GEMM v3 (R16, proven): one block per 16n x 32m C-tile; 8 waves =
// K=512 splits; w-fragment shared by both m-halves; LDS reduce; no atomics.
// ---------------------------------------------------------------------------
__device__ __forceinline__ short f2bfs(float f) {
    __hip_bfloat16 h = __float2bfloat16(f);
    unsigned short u;
    __builtin_memcpy(&u, &h, 2);
    return (short)u;
}
__device__ __forceinline__ bf16x8 cvt8(float4 a, float4 b) {
    bf16x8 r;
    r[0] = f2bfs(a.x); r[1] = f2bfs(a.y); r[2] = f2bfs(a.z); r[3] = f2bfs(a.w);
    r[4] = f2bfs(b.x); r[5] = f2bfs(b.y); r[6] = f2bfs(b.z); r[7] = f2bfs(b.w);
    return r;
}

__device__ __forceinline__ void mfma_block8(
    const float* __restrict__ xp0, const float* __restrict__ xp1,
    const float* __restrict__ wp, float* __restrict__ dst, int dstr, int n0)
{
    __shared__ float red[8][64][8];
    int wave = threadIdx.x >> 6, lane = threadIdx.x & 63;
    f32x4 acc0 = {0.f, 0.f, 0.f, 0.f};
    f32x4 acc1 = {0.f, 0.f, 0.f, 0.f};
#pragma unroll 4
    for (int s = 0; s < 16; ++s) {
        float4 wa  = *(const float4*)(wp  + s * 32);
        float4 wb  = *(const float4*)(wp  + s * 32 + 4);
        float4 x0a = *(const float4*)(xp0 + s * 32);
        float4 x0b = *(const float4*)(xp0 + s * 32 + 4);
        float4 x1a = *(const float4*)(xp1 + s * 32);
        float4 x1b = *(const float4*)(xp1 + s * 32 + 4);
        bf16x8 wf = cvt8(wa, wb);
        acc0 = __builtin_amdgcn_mfma_f32_16x16x32_bf16(cvt8(x0a, x0b), wf, acc0, 0, 0, 0);
        acc1 = __builtin_amdgcn_mfma_f32_16x16x32_bf16(cvt8(x1a, x1b), wf, acc1, 0, 0, 0);
    }
#pragma unroll
    for (int j = 0; j < 4; ++j) { red[wave][lane][j] = acc0[j]; red[wave][lane][4 + j] = acc1[j]; }
    __syncthreads();
    if (threadIdx.x < 128) {
        int l = threadIdx.x & 63, half = threadIdx.x >> 6;
        int ccol = n0 + (l & 15);
        int rbase = half * 16 + ((l >> 4) << 2);
#pragma unroll
        for (int j = 0; j < 4; ++j) {
            int e = (half << 2) + j;
            float s = red[0][l][e] + red[1][l][e] + red[2][l][e] + red[3][l][e]
                    + red[4][l][e] + red[5][l][e] + red[6][l][e] + red[7][l][e];
            dst[(size_t)(rbase + j) * dstr + ccol] = s;
        }
    }
}

// grid = 384 blocks x 512 thr (256 q-tiles, 64 k, 64 v)
__global__ __launch_bounds__(512) void qkv_mfma(
    const float* __restrict__ x, const float* __restrict__ wq,
    const float* __restrict__ wk, const float* __restrict__ wv,
    float* __restrict__ qb, float* __restrict__ knb, float* __restrict__ vnb)
{
    int nt = blockIdx.x;
    int wave = threadIdx.x >> 6, lane = threadIdx.x & 63;
    const float* w; float* dst; int dstr; int n0;
    if (nt < 256)      { w = wq; n0 = nt * 16;         dst = qb;  dstr = 4096; }
    else if (nt < 320) { w = wk; n0 = (nt - 256) * 16; dst = knb; dstr = 1024; }
    else               { w = wv; n0 = (nt - 320) * 16; dst = vnb; dstr = 1024; }
    int row = lane & 15, kq = (lane >> 4) << 3;
    int kbase = wave << 9;
    const float* xp0 = x + (size_t)row * 4096 + kbase + kq;
    const float* xp1 = xp0 + (size_t)16 * 4096;
    const float* wp  = w + (size_t)(n0 + row) * 4096 + kbase + kq;
    mfma_block8(xp0, xp1, wp, dst, dstr, n0);
}

// grid = 256 blocks x 512 thr
__global__ __launch_bounds__(512) void wo_mfma(
    const float* __restrict__ attn, const float* __restrict__ wo,
    float* __restrict__ out)
{
    int nt = blockIdx.x;
    int wave = threadIdx.x >> 6, lane = threadIdx.x & 63;
    int n0 = nt * 16;
    int row = lane & 15, kq = (lane >> 4) << 3;
    int kbase = wave << 9;
    const float* xp0 = attn + (size_t)row * 4096 + kbase + kq;
    const float* xp1 = xp0 + (size_t)16 * 4096;
    const float* wp  = wo + (size_t)(n0 + row) * 4096 + kbase + kq;
    mfma_block8(xp0, xp1, wp, out, 4096, n0);
}

// ---------------------------------------------------------------------------
// Flash-decode attention v10 (R19 best, restored). 128-thr blocks (2 kv-heads),
// chunk 128, contiguous lane slicing (lane l owns dims {4l..4l+3, 64+4l..}),
// lane-local fused rope, explicit new-token tail, 2-deep named-scalar
// prefetch (rule #20). v11's cohesion barriers regressed +16us (vmcnt(0)
// drain per barrier kills the prefetch — the R8/m97 mechanism).
// ---------------------------------------------------------------------------
#define MUL4(V, S) { V.x *= S; V.y *= S; V.z *= S; V.w *= S; }
#define FMA4(O, P, V) { O.x = fmaf(P, V.x, O.x); O.y = fmaf(P, V.y, O.y); \
                        O.z = fmaf(P, V.z, O.z); O.w = fmaf(P, V.w, O.w); }
#define DOT8(S, QA, QB, K0, K1) { \
    S = fmaf(QA.x, K0.x, S); S = fmaf(QA.y, K0.y, S); \
    S = fmaf(QA.z, K0.z, S); S = fmaf(QA.w, K0.w, S); \
    S = fmaf(QB.x, K1.x, S); S = fmaf(QB.y, K1.y, S); \
    S = fmaf(QB.z, K1.z, S); S = fmaf(QB.w, K1.w, S); }
#define RED16(X) { X += __shfl_xor(X, 1, 64); X += __shfl_xor(X, 2, 64); \
                   X += __shfl_xor(X, 4, 64); X += __shfl_xor(X, 8, 64); }
#define REDG_SUM(X) { X += __shfl_xor(X, 16, 64); X += __shfl_xor(X, 32, 64); }
#define REDG_MAX(X) { X = fmaxf(X, __shfl_xor(X, 16, 64)); \
                      X = fmaxf(X, __shfl_xor(X, 32, 64)); }
#define REDG_SUM4(V) { REDG_SUM(V.x) REDG_SUM(V.y) REDG_SUM(V.z) REDG_SUM(V.w) }

// lane-local rope: A = dims 4i..4i+3 (first half), B = dims 64+4i.. (second)
#define ROPE8(A, B) { \
    float2 c0 = cs[isl + 0], c1 = cs[isl + 1], c2 = cs[isl + 2], c3 = cs[isl + 3]; \
    float a0 = A.x, a1 = A.y, a2 = A.z, a3 = A.w; \
    A.x = fmaf(-B.x, c0.y, a0 * c0.x); \
    A.y = fmaf(-B.y, c1.y, a1 * c1.x); \
    A.z = fmaf(-B.z, c2.y, a2 * c2.x); \
    A.w = fmaf(-B.w, c3.y, a3 * c3.x); \
    B.x = fmaf(a0, c0.y, B.x * c0.x); \
    B.y = fmaf(a1, c1.y, B.y * c1.x); \
    B.z = fmaf(a2, c2.y, B.z * c2.x); \
    B.w = fmaf(a3, c3.y, B.w * c3.x); }

#define ALOADR(S, r_) { \
    int sl = ss[((r_) << 2) + g]; \
    const float* kp = kc + (size_t)sl * 1024 + hoff + isl; \
    const float* vp = vc + (size_t)sl * 1024 + hoff + isl; \
    S##k0 = *(const float4*)(kp); S##k1 = *(const float4*)(kp + 64); \
    S##v0 = *(const float4*)(vp); S##v1 = *(const float4*)(vp + 64); }

#define OUPD(s_, m_, l_, Oa_, Ob_, V0_, V1_, vld_) { \
    if (s_ > m_) { \
        float c_ = __expf(m_ - s_); \
        l_ *= c_; MUL4(Oa_, c_) MUL4(Ob_, c_) \
        m_ = s_; \
    } \
    float pe_ = vld_ ? __expf(s_ - m_) : 0.f; \
    l_ += pe_; \
    FMA4(Oa_, pe_, V0_) FMA4(Ob_, pe_, V1_) }

#define ACOMP(S, r_) { \
    float s0 = 0.f, s1 = 0.f, s2 = 0.f, s3 = 0.f; \
    DOT8(s0, q0a, q0b, S##k0, S##k1) \
    DOT8(s1, q1a, q1b, S##k0, S##k1) \
    DOT8(s2, q2a, q2b, S##k0, S##k1) \
    DOT8(s3, q3a, q3b, S##k0, S##k1) \
    RED16(s0) RED16(s1) RED16(s2) RED16(s3) \
    int vld = (((r_) << 2) + g) < cend; \
    if (!vld) { s0 = s1 = s2 = s3 = -INFINITY; } \
    OUPD(s0, m0, l0, o0a, o0b, S##v0, S##v1, vld) \
    OUPD(s1, m1, l1, o1a, o1b, S##v0, S##v1, vld) \
    OUPD(s2, m2, l2, o2a, o2b, S##v0, S##v1, vld) \
    OUPD(s3, m3, l3, o3a, o3b, S##v0, S##v1, vld) }

__global__ __launch_bounds__(128, 1) void attn_kernel(
    const float* __restrict__ kc, const float* __restrict__ vc,
    const float* __restrict__ qb, const float* __restrict__ knb,
    const float* __restrict__ vnb,
    const int* __restrict__ btab, const int* __restrict__ lens,
    float* __restrict__ part)
{
    int bid = blockIdx.x;
    int hp = bid & 3;                   // head-pair within (b,c)
    int idx = bid >> 2;
    int c = idx >> 5, b = idx & 31;     // chunk-major for CU balance
    int len = lens[b];
    int p0 = c << 7;
    if (p0 >= len) return;
    int last = len - 1;                 // new-token position
    int cend = min(last - p0, 128);     // cached positions in this chunk
    int hasTail = (last - p0) < 128;
    int nr = (cend + 3) >> 2;

    __shared__ int ss[128];
    __shared__ float2 cs[64];           // rope cos/sin for pos = last

    int t = threadIdx.x;                // 0..127
    int h = (hp << 1) | (t >> 6);       // global kv-head 0..7
    int lane = t & 63;
    int g = lane >> 4;                  // position-in-round 0..3
    int i = lane & 15;
    int isl = i << 2;                   // dim slice base (4 floats; +64 pair)
    int hoff = h * 128;

    if (t < 64) {                       // rope table: d' = t
        float inv = exp2f(-(float)t * 0.20762050593046014f);
        float fr = (float)last * inv;
        float s_, c_;
        sincosf(fr, &s_, &c_);
        cs[t] = make_float2(c_, s_);
    } else {                            // slot table (all entries valid slots)
        int idx2 = (t - 64) << 1;
        int p = p0 + idx2;
        int bt = btab[b * 128 + (p >> 4)];
        ss[idx2]     = bt * 16 + (p & 15);
        ss[idx2 + 1] = bt * 16 + (p & 15) + 1;
    }
    __syncthreads();

    // q for this kv-head's 4 GQA heads: load (contig halves), ROPE, prescale
    const float scale = 0.08838834764831845f;   // 1/sqrt(128)
    const float* qrow = qb + (size_t)b * 4096 + (size_t)h * 512;
    float4 q0a = *(const float4*)(qrow + isl),       q0b = *(const float4*)(qrow + 64 + isl);
    float4 q1a = *(const float4*)(qrow + 128 + isl), q1b = *(const float4*)(qrow + 192 + isl);
    float4 q2a = *(const float4*)(qrow + 256 + isl), q2b = *(const float4*)(qrow + 320 + isl);
    float4 q3a = *(const float4*)(qrow + 384 + isl), q3b = *(const float4*)(qrow + 448 + isl);
    ROPE8(q0a, q0b) ROPE8(q1a, q1b) ROPE8(q2a, q2b) ROPE8(q3a, q3b)
    MUL4(q0a, scale) MUL4(q0b, scale) MUL4(q1a, scale) MUL4(q1b, scale)
    MUL4(q2a, scale) MUL4(q2b, scale) MUL4(q3a, scale) MUL4(q3b, scale)

    float m0 = -INFINITY, m1 = -INFINITY, m2 = -INFINITY, m3 = -INFINITY;
    float l0 = 0.f, l1 = 0.f, l2 = 0.f, l3 = 0.f;
    float4 o0a = {0,0,0,0}, o0b = {0,0,0,0}, o1a = {0,0,0,0}, o1b = {0,0,0,0};
    float4 o2a = {0,0,0,0}, o2b = {0,0,0,0}, o3a = {0,0,0,0}, o3b = {0,0,0,0};

    // ---- tail: the new-token position (rope k_new in-reg; v not roped) ----
    if (hasTail) {
        const float* kn = knb + ((size_t)b * 8 + h) * 128 + isl;
        const float* vn = vnb + ((size_t)b * 8 + h) * 128 + isl;
        float4 tk0 = *(const float4*)(kn), tk1 = *(const float4*)(kn + 64);
        float4 tv0 = *(const float4*)(vn), tv1 = *(const float4*)(vn + 64);
        ROPE8(tk0, tk1)
        float s0 = 0.f, s1 = 0.f, s2 = 0.f, s3 = 0.f;
        DOT8(s0, q0a, q0b, tk0, tk1)
        DOT8(s1, q1a, q1b, tk0, tk1)
        DOT8(s2, q2a, q2b, tk0, tk1)
        DOT8(s3, q3a, q3b, tk0, tk1)
        RED16(s0) RED16(s1) RED16(s2) RED16(s3)
        int vld = (g == 0);
        if (!vld) { s0 = s1 = s2 = s3 = -INFINITY; }
        OUPD(s0, m0, l0, o0a, o0b, tv0, tv1, vld)
        OUPD(s1, m1, l1, o1a, o1b, tv0, tv1, vld)
        OUPD(s2, m2, l2, o2a, o2b, tv0, tv1, vld)
        OUPD(s3, m3, l3, o3a, o3b, tv0, tv1, vld)
    }

    // ---- main loop: pure cache streaming, 2-deep named-reg prefetch ----
    float4 ak0, ak1, av0, av1;
    float4 bk0, bk1, bv0, bv1;
    if (nr > 0) {
        ALOADR(a, 0)
        if (1 < nr) ALOADR(b, 1)
        for (int r = 0; r < nr; r += 2) {
            ACOMP(a, r)
            if (r + 2 < nr) ALOADR(a, r + 2)
            if (r + 1 >= nr) break;
            ACOMP(b, r + 1)
            if (r + 3 < nr) ALOADR(b, r + 3)
        }
    }

    // merge the 4 subgroup partial softmaxes (once per wave)
    float M0 = m0, M1 = m1, M2 = m2, M3 = m3;
    REDG_MAX(M0) REDG_MAX(M1) REDG_MAX(M2) REDG_MAX(M3)
    float w0 = __expf(m0 - M0), w1 = __expf(m1 - M1);
    float w2 = __expf(m2 - M2), w3 = __expf(m3 - M3);
    float L0 = w0 * l0, L1 = w1 * l1, L2 = w2 * l2, L3 = w3 * l3;
    REDG_SUM(L0) REDG_SUM(L1) REDG_SUM(L2) REDG_SUM(L3)
    MUL4(o0a, w0) MUL4(o0b, w0) MUL4(o1a, w1) MUL4(o1b, w1)
    MUL4(o2a, w2) MUL4(o2b, w2) MUL4(o3a, w3) MUL4(o3b, w3)
    REDG_SUM4(o0a) REDG_SUM4(o0b) REDG_SUM4(o1a) REDG_SUM4(o1b)
    REDG_SUM4(o2a) REDG_SUM4(o2b) REDG_SUM4(o3a) REDG_SUM4(o3b)

    // partial layout: per (b,h,c): 4 heads x 132 floats [O[128], m, l, pad2]
    float* pgb = part + (size_t)(((b * 8 + h) * 16 + c) * 4) * 132;
    if (lane < 16) {
        *(float4*)(pgb +       isl) = o0a; *(float4*)(pgb +  64 + isl) = o0b;
        *(float4*)(pgb + 132 + isl) = o1a; *(float4*)(pgb + 196 + isl) = o1b;
        *(float4*)(pgb + 264 + isl) = o2a; *(float4*)(pgb + 328 + isl) = o2b;
        *(float4*)(pgb + 396 + isl) = o3a; *(float4*)(pgb + 460 + isl) = o3b;
    }
    if (lane == 0) {
        pgb[128] = M0; pgb[129] = L0;
        pgb[260] = M1; pgb[261] = L1;
        pgb[392] = M2; pgb[393] = L2;
        pgb[524] = M3; pgb[525] = L3;
    }
}

// grid = 256 (b*8+h), block = 256 (4 q-heads x 64 lanes)
__global__ __launch_bounds__(256) void combine_kernel(
    const float* __restrict__ part, const int* __restrict__ lens,
    float* __restrict__ attn)
{
    int b = blockIdx.x >> 3, h = blockIdx.x & 7;
    int t = threadIdx.x;
    int g = t >> 6, lane = t & 63;
    int len = lens[b];
    int nch = (len + 127) >> 7;
    const float* base = part + (size_t)(b * 8 + h) * 8448 + (size_t)g * 132;
    float M = -INFINITY;
    for (int cc = 0; cc < nch; ++cc)
        M = fmaxf(M, base[(size_t)cc * 528 + 128]);
    float denom = 0.f, a0 = 0.f, a1 = 0.f;
    int d0 = lane << 1;
    for (int cc = 0; cc < nch; ++cc) {
        const float* pg = base + (size_t)cc * 528;
        float w = __expf(pg[128] - M);
        denom += w * pg[129];
        a0 += w * pg[d0];
        a1 += w * pg[d0 + 1];
    }
    float inv = 1.f / denom;
    float* dst = attn + (size_t)b * 4096 + (size_t)(h * 4 + g) * 128 + d0;
    dst[0] = a0 * inv;
    dst[1] = a1 * inv;
}

// ---------------------------------------------------------------------------
// Workspace (floats): qb[32][4096] @0, knb[32*1024] @131072, vnb @163840,
// attn[32][4096] @196608, part[32*8*16*4*132] @327680 (~8.7MB).
// NO memsets: all outputs fully written (no atomics anywhere). 4 dispatches.
// ---------------------------------------------------------------------------
extern "C" void kernel_launch(void* const* d_in, const int* in_sizes, int n_in,
                              void* d_out, int out_size, void* d_ws, size_t ws_size,
                              hipStream_t stream)
{
    const float* x   = (const float*)d_in[0];
    const float* wq  = (const float*)d_in[1];
    const float* wk  = (const float*)d_in[2];
    const float* wv  = (const float*)d_in[3];
    const float* wo  = (const float*)d_in[4];
    const float* kc  = (const float*)d_in[5];
    const float* vc  = (const float*)d_in[6];
    const int* btab  = (const int*)d_in[8];
    const int* lens  = (const int*)d_in[10];

    float* qb   = (float*)d_ws;
    float* knb  = qb  + 32 * 4096;
    float* vnb  = knb + 32 * 1024;
    float* attn = vnb + 32 * 1024;
    float* part = attn + 32 * 4096;
    float* outp = (float*)d_out;

    qkv_mfma<<<384, 512, 0, stream>>>(x, wq, wk, wv, qb, knb, vnb);
    attn_kernel<<<2048, 128, 0, stream>>>(kc, vc, qb, knb, vnb, btab, lens, part);
    combine_kernel<<<256, 256, 0, stream>>>(part, lens, attn);
    wo_mfma<<<256, 512, 0, stream>>>(attn, wo, outp);
}